// Round 10
// baseline (222.976 us; speedup 1.0000x reference)
//
#include <hip/hip_runtime.h>

// STGCN-LSTM-Node on MI355X (gfx950).
// T=128, N=32, E=512/t, IN_C=64, HID=128, SEQ=16, heads (4,2).
// d_out is FLOAT32: [out0 16384][out1 8192][targets 16384].
//
// R19: merged L1/L2 recurrence. R18 (83us) was bubble-bound: 6K cyc/step vs
//   ~600-cyc dependency path; 8 symmetric waves stall together at the same
//   barrier/ds_read/exp points. Iteration i now runs B-step i AND D-step
//   i-1 (D consumes h1[i-1] just produced; both share one LDS A-frag read):
//   32 barriers -> 19, 3x work per barrier window -> bubbles filled.
//   Registers: Whh1 in LDS (R16 swizzle), Wih2+Whh2 in 128 pinned AGPRs
//   (R18), ~100 VGPR -> fits the 256 budget. xg1 -> global ws (R16 path,
//   L2-local, prefetched); h1seq -> 2-slot LDS ring. LDS 148.5KB keeps
//   1 block/CU (the 256-reg budget R10-R13 lacked).
//
// flags[0]=1: float inputs stored as bf16-u16; =0: f32
// flags[1]=1: edge_index int64; =0: int32

#define T_STEPS 128
#define HID     128
#define G4      512
#define SEQ     16

typedef unsigned short u16;
typedef unsigned int   u32;
typedef __attribute__((ext_vector_type(8))) short bf16x8;
typedef __attribute__((ext_vector_type(4))) float f32x4;
typedef __attribute__((ext_vector_type(4))) u16   u16x4;

__device__ __forceinline__ float bf2f(u16 u) {
  union { u32 i; float f; } v; v.i = ((u32)u) << 16; return v.f;
}
__device__ __forceinline__ u16 f2bf(float f) {
  union { u32 i; float f; } v; v.f = f;
  const u32 i = v.i;
  return (u16)((i + 0x7fffu + ((i >> 16) & 1u)) >> 16);
}
__device__ __forceinline__ float sigm(float x) {
  return __builtin_amdgcn_rcpf(1.f + __expf(-x));
}
__device__ __forceinline__ float tanh_fast(float x) {
  return 1.f - 2.f * __builtin_amdgcn_rcpf(1.f + __expf(2.f * x));
}
__device__ __forceinline__ float clampg(float x) { return fminf(fmaxf(x, -25.f), 25.f); }

__device__ __forceinline__ float ldf(const void* p, size_t i, int isbf) {
  return isbf ? bf2f(((const u16*)p)[i]) : ((const float*)p)[i];
}
__device__ __forceinline__ bf16x8 ld8(const void* p, size_t o, int isbf) {
  if (isbf) return *(const bf16x8*)((const u16*)p + o);
  const float* f = (const float*)p + o;
  bf16x8 r;
  #pragma unroll
  for (int j = 0; j < 8; ++j) r[j] = (short)f2bf(f[j]);
  return r;
}
__device__ __forceinline__ int lde(const int* ei, int idx, int i64) {
  return i64 ? ei[idx * 2] : ei[idx];
}

// ----------------------------------------- K1: GCN (MFMA, self-detect) -----
__global__ __launch_bounds__(512) void gcn_kernel(
    const void* __restrict__ x, const int* __restrict__ ei,
    const void* __restrict__ W1, const void* __restrict__ b1,
    const void* __restrict__ W2, const void* __restrict__ b2,
    u32* __restrict__ flags, u16* __restrict__ Hb)
{
  const int t = blockIdx.x;
  const int tid = threadIdx.x;
  const int wave = tid >> 6, lane = tid & 63;
  const int quad = lane >> 4, l16 = lane & 15;

  __shared__ u16 sXA[32 * 72];
  __shared__ u16 sW1T[128 * 72];
  __shared__ u16 sW2T[128 * 136];
  __shared__ u16 sAmB[32 * 40];
  __shared__ float sAm[32 * 33];
  __shared__ u16 sT[128 * 40];
  __shared__ u16 sHA[32 * 136];
  __shared__ int sdeg[32];
  __shared__ float sdinv[32];
  __shared__ int dc1, dc2;

  if (tid == 0) { dc1 = 0; dc2 = 0; }
  __syncthreads();
  if (tid < 256) {
    const u32 w = ((const u32*)x)[tid];
    const u16 lo = (u16)(w & 0xffffu);
    const float a = fabsf(bf2f(lo));
    if (lo != 0 && a >= 9.5e-7f && a <= 8.f) atomicAdd(&dc1, 1);
    if (ei[2 * tid + 1] != 0) atomicAdd(&dc2, 1);
  }
  __syncthreads();
  const int isbf = (dc1 >= 128) ? 1 : 0;
  const int i64  = (dc2 < 8) ? 1 : 0;
  if (t == 0 && tid == 0) { flags[0] = (u32)isbf; flags[1] = (u32)i64; }

  for (int idx = tid; idx < 2048; idx += 512) {
    const int m = idx >> 6, k = idx & 63;
    sXA[m * 72 + k] = f2bf(ldf(x, (size_t)t * 2048 + idx, isbf));
  }
  for (int idx = tid; idx < 8192; idx += 512) {
    const int k = idx >> 7, nn = idx & 127;
    sW1T[nn * 72 + k] = f2bf(ldf(W1, idx, isbf));
  }
  for (int idx = tid; idx < 16384; idx += 512) {
    const int k = idx >> 7, nn = idx & 127;
    sW2T[nn * 136 + k] = f2bf(ldf(W2, idx, isbf));
  }
  for (int i = tid; i < 32 * 33; i += 512) sAm[i] = 0.f;
  if (tid < 32) sdeg[tid] = 0;
  __syncthreads();
  if (tid < 512) {
    const int cd = lde(ei, t * 1024 + 512 + tid, i64);
    if ((u32)cd < 32u) atomicAdd(&sdeg[cd], 1);
  }
  __syncthreads();
  if (tid < 32) sdinv[tid] = rsqrtf((float)(sdeg[tid] + 1));
  __syncthreads();
  if (tid < 512) {
    const int r  = lde(ei, t * 1024 + tid, i64);
    const int cd = lde(ei, t * 1024 + 512 + tid, i64);
    if ((u32)r < 32u && (u32)cd < 32u)
      atomicAdd(&sAm[cd * 33 + r], sdinv[r] * sdinv[cd]);
  }
  if (tid < 32) atomicAdd(&sAm[tid * 33 + tid], sdinv[tid] * sdinv[tid]);
  __syncthreads();

  for (int idx = tid; idx < 1024; idx += 512) {
    const int m = idx >> 5, k = idx & 31;
    sAmB[m * 40 + k] = f2bf(sAm[m * 33 + k]);
  }
  // GEMM1
  {
    const int nc = wave * 16 + l16;
    f32x4 c0 = {0.f,0.f,0.f,0.f}, c1 = {0.f,0.f,0.f,0.f};
    #pragma unroll
    for (int kc = 0; kc < 2; ++kc) {
      const bf16x8 a0 = *(const bf16x8*)&sXA[l16 * 72 + kc * 32 + quad * 8];
      const bf16x8 a1 = *(const bf16x8*)&sXA[(16 + l16) * 72 + kc * 32 + quad * 8];
      const bf16x8 bb = *(const bf16x8*)&sW1T[nc * 72 + kc * 32 + quad * 8];
      c0 = __builtin_amdgcn_mfma_f32_16x16x32_bf16(a0, bb, c0, 0, 0, 0);
      c1 = __builtin_amdgcn_mfma_f32_16x16x32_bf16(a1, bb, c1, 0, 0, 0);
    }
    #pragma unroll
    for (int r = 0; r < 4; ++r) {
      sT[nc * 40 + quad * 4 + r]      = f2bf(c0[r]);
      sT[nc * 40 + 16 + quad * 4 + r] = f2bf(c1[r]);
    }
  }
  __syncthreads();
  // GEMM2
  {
    const int nc = wave * 16 + l16;
    const bf16x8 a0 = *(const bf16x8*)&sAmB[l16 * 40 + quad * 8];
    const bf16x8 a1 = *(const bf16x8*)&sAmB[(16 + l16) * 40 + quad * 8];
    const bf16x8 bb = *(const bf16x8*)&sT[nc * 40 + quad * 8];
    f32x4 c0 = {0.f,0.f,0.f,0.f}, c1 = {0.f,0.f,0.f,0.f};
    c0 = __builtin_amdgcn_mfma_f32_16x16x32_bf16(a0, bb, c0, 0, 0, 0);
    c1 = __builtin_amdgcn_mfma_f32_16x16x32_bf16(a1, bb, c1, 0, 0, 0);
    const float bv = ldf(b1, nc, isbf);
    #pragma unroll
    for (int r = 0; r < 4; ++r) {
      float v0 = c0[r] + bv, v1 = c1[r] + bv;
      sHA[(quad * 4 + r) * 136 + nc]      = f2bf(v0 > 0.f ? v0 : 0.f);
      sHA[(16 + quad * 4 + r) * 136 + nc] = f2bf(v1 > 0.f ? v1 : 0.f);
    }
  }
  __syncthreads();
  // GEMM3
  {
    const int nc = wave * 16 + l16;
    f32x4 c0 = {0.f,0.f,0.f,0.f}, c1 = {0.f,0.f,0.f,0.f};
    #pragma unroll
    for (int kc = 0; kc < 4; ++kc) {
      const bf16x8 a0 = *(const bf16x8*)&sHA[l16 * 136 + kc * 32 + quad * 8];
      const bf16x8 a1 = *(const bf16x8*)&sHA[(16 + l16) * 136 + kc * 32 + quad * 8];
      const bf16x8 bb = *(const bf16x8*)&sW2T[nc * 136 + kc * 32 + quad * 8];
      c0 = __builtin_amdgcn_mfma_f32_16x16x32_bf16(a0, bb, c0, 0, 0, 0);
      c1 = __builtin_amdgcn_mfma_f32_16x16x32_bf16(a1, bb, c1, 0, 0, 0);
    }
    #pragma unroll
    for (int r = 0; r < 4; ++r) {
      sT[nc * 40 + quad * 4 + r]      = f2bf(c0[r]);
      sT[nc * 40 + 16 + quad * 4 + r] = f2bf(c1[r]);
    }
  }
  __syncthreads();
  // GEMM4
  {
    const int nc = wave * 16 + l16;
    const bf16x8 a0 = *(const bf16x8*)&sAmB[l16 * 40 + quad * 8];
    const bf16x8 a1 = *(const bf16x8*)&sAmB[(16 + l16) * 40 + quad * 8];
    const bf16x8 bb = *(const bf16x8*)&sT[nc * 40 + quad * 8];
    f32x4 c0 = {0.f,0.f,0.f,0.f}, c1 = {0.f,0.f,0.f,0.f};
    c0 = __builtin_amdgcn_mfma_f32_16x16x32_bf16(a0, bb, c0, 0, 0, 0);
    c1 = __builtin_amdgcn_mfma_f32_16x16x32_bf16(a1, bb, c1, 0, 0, 0);
    const float bv = ldf(b2, nc, isbf);
    #pragma unroll
    for (int r = 0; r < 4; ++r) {
      float v0 = c0[r] + bv, v1 = c1[r] + bv;
      Hb[((size_t)t * 32 + quad * 4 + r) * 128 + nc]      = f2bf(v0 > 0.f ? v0 : 0.f);
      Hb[((size_t)t * 32 + 16 + quad * 4 + r) * 128 + nc] = f2bf(v1 > 0.f ? v1 : 0.f);
    }
  }
}

// --------------------- K2 (R19): merged L1+L2 recurrence -------------------
// LDS: sW 512x128 bf16 (Whh1, XOR-swizzled) + h1 ring[2] + h2 ring[2].
// xg1 gate-packed in global ws (written phase A, L2-local, prefetched).
// Wih2+Whh2 in 128 pinned AGPRs. Iteration i: B-step i + D-step i-1 share
// the h1[i-1] A-fragment; 1 barrier per iteration (19 total vs R18's 35).
__global__ __launch_bounds__(512) void lstm_kernel(
    const void* __restrict__ Wih1, const void* __restrict__ Whh1,
    const void* __restrict__ Wih2, const void* __restrict__ Whh2,
    const void* __restrict__ bih1, const void* __restrict__ bhh1,
    const void* __restrict__ bih2, const void* __restrict__ bhh2,
    const u16* __restrict__ Hb, const u32* __restrict__ flags,
    u16* __restrict__ XG1, u16* __restrict__ HLAST)
{
  const int isbf = (int)flags[0];
  const int b = blockIdx.x;
  const int n = b & 31, wg = b >> 5;
  const int t0 = wg * 16;
  const int tid = threadIdx.x;
  const int wave = tid >> 6, lane = tid & 63;
  const int quad = lane >> 4, l16 = lane & 15;
  const int col = wave * 16 + l16;

  __shared__ __align__(16) u16 sW[512 * 128];     // 131072 B (Whh1 swizzled)
  __shared__ __align__(16) u16 ring1[2][16 * 136];// h1 ping-pong (8704 B)
  __shared__ __align__(16) u16 ring2[2][16 * 136];// h2 ping-pong (8704 B)
  u16* sHB = (u16*)ring1;   // [32][136] alias, phase A only

  u16* xg1 = XG1 + (size_t)b * (32 * 512);        // [row][col][gate] u16
  const size_t Wbase = (size_t)n * (G4 * HID);

  // ---- stage Hb window + Whh1->sW (disjoint regions; one barrier) ----
  for (int idx = tid; idx < 32 * 128; idx += 512) {
    const int row = idx >> 7, cc = idx & 127;
    const int tp = t0 - 15 + row;
    sHB[row * 136 + cc] =
        (tp >= 0 && tp < T_STEPS) ? Hb[((size_t)tp * 32 + n) * 128 + cc] : (u16)0;
  }
  {
    const int g = tid;
    const size_t gb = Wbase + (size_t)g * HID;
    #pragma unroll
    for (int c = 0; c < 16; ++c)
      *(bf16x8*)&sW[g * 128 + ((c ^ (g & 15)) * 8)] = ld8(Whh1, gb + c * 8, isbf);
  }
  float bbv[4];
  #pragma unroll
  for (int t = 0; t < 4; ++t)
    bbv[t] = ldf(bih1, n * 512 + t * 128 + col, isbf) +
             ldf(bhh1, n * 512 + t * 128 + col, isbf);
  __syncthreads();

  // ---- phase A: XG1 = Wih1 @ HbWin + (bih1+bhh1), gate-packed -> ws ----
  {
    u16 pk[2][4][4];   // [grp][r][gate]
    #pragma unroll
    for (int t = 0; t < 4; ++t) {
      const size_t gb = Wbase + (size_t)(t * 128 + col) * HID;
      f32x4 a0 = {0.f,0.f,0.f,0.f}, a1 = {0.f,0.f,0.f,0.f};
      #pragma unroll
      for (int kc = 0; kc < 4; ++kc) {
        const bf16x8 wf = ld8(Wih1, gb + kc * 32 + quad * 8, isbf);
        const bf16x8 h0 = *(const bf16x8*)&sHB[l16 * 136 + kc * 32 + quad * 8];
        const bf16x8 h1v = *(const bf16x8*)&sHB[(16 + l16) * 136 + kc * 32 + quad * 8];
        a0 = __builtin_amdgcn_mfma_f32_16x16x32_bf16(h0, wf, a0, 0, 0, 0);
        a1 = __builtin_amdgcn_mfma_f32_16x16x32_bf16(h1v, wf, a1, 0, 0, 0);
      }
      #pragma unroll
      for (int r = 0; r < 4; ++r) {
        pk[0][r][t] = f2bf(a0[r] + bbv[t]);
        pk[1][r][t] = f2bf(a1[r] + bbv[t]);
      }
    }
    #pragma unroll
    for (int g2 = 0; g2 < 2; ++g2)
      #pragma unroll
      for (int r = 0; r < 4; ++r) {
        u16x4 v = {pk[g2][r][0], pk[g2][r][1], pk[g2][r][2], pk[g2][r][3]};
        *(u16x4*)&xg1[((size_t)(g2 * 16 + quad * 4 + r) * 128 + col) * 4] = v;
      }
  }

  // ---- Wih2 + Whh2 -> 128 pinned AGPRs ----
  bf16x8 bfri[4][4], bfrh[4][4];
  #pragma unroll
  for (int t = 0; t < 4; ++t) {
    const size_t gb = Wbase + (size_t)(t * 128 + col) * HID;
    #pragma unroll
    for (int kc = 0; kc < 4; ++kc) {
      bfri[t][kc] = ld8(Wih2, gb + kc * 32 + quad * 8, isbf);
      bfrh[t][kc] = ld8(Whh2, gb + kc * 32 + quad * 8, isbf);
    }
  }
  #pragma unroll
  for (int t = 0; t < 4; ++t)
    #pragma unroll
    for (int kc = 0; kc < 4; ++kc) {
      asm volatile("" : "+a"(bfri[t][kc]));
      asm volatile("" : "+a"(bfrh[t][kc]));
    }
  float bias2[4];
  #pragma unroll
  for (int t = 0; t < 4; ++t)
    bias2[t] = ldf(bih2, n * 512 + t * 128 + col, isbf) +
               ldf(bhh2, n * 512 + t * 128 + col, isbf);

  float c1v[4] = {0.f, 0.f, 0.f, 0.f};
  float c2v[4] = {0.f, 0.f, 0.f, 0.f};
  __syncthreads();   // xg1 drained; sHB reads done; sW ready

  // ---- merged loop: iteration i = B-step i (i<16) + D-step i-1 (i>=1) ----
  for (int i = 0; i <= SEQ; ++i) {
    const bool doB = (i < SEQ);
    const bool doD = (i >= 1);

    // B-gate prefetch (global, L2-local)
    u16x4 gvb[4];
    if (doB) {
      #pragma unroll
      for (int r = 0; r < 4; ++r)
        gvb[r] = *(const u16x4*)&xg1[((size_t)(quad * 4 + r + i) * 128 + col) * 4];
    }
    // shared A-fragment: h1[i-1]
    bf16x8 af[4];
    if (i > 0) {
      #pragma unroll
      for (int kc = 0; kc < 4; ++kc)
        af[kc] = *(const bf16x8*)&ring1[(i - 1) & 1][l16 * 136 + kc * 32 + quad * 8];
    }

    // B: accB = h1[i-1] @ Whh1 (LDS swizzled B-operand)
    f32x4 accB[4];
    #pragma unroll
    for (int t = 0; t < 4; ++t) { accB[t][0]=0.f; accB[t][1]=0.f; accB[t][2]=0.f; accB[t][3]=0.f; }
    if (doB && i > 0) {
      #pragma unroll
      for (int t = 0; t < 4; ++t)
        #pragma unroll
        for (int kc = 0; kc < 4; ++kc)
          accB[t] = __builtin_amdgcn_mfma_f32_16x16x32_bf16(
              af[kc], *(const bf16x8*)&sW[(t * 128 + col) * 128 + (((kc * 4 + quad) ^ l16) * 8)],
              accB[t], 0, 0, 0);
    }
    // D: accD = h1[i-1] @ Wih2 + h2[i-2] @ Whh2 (AGPR operands)
    f32x4 accD[4];
    #pragma unroll
    for (int t = 0; t < 4; ++t) { accD[t][0]=0.f; accD[t][1]=0.f; accD[t][2]=0.f; accD[t][3]=0.f; }
    if (doD) {
      #pragma unroll
      for (int t = 0; t < 4; ++t)
        #pragma unroll
        for (int kc = 0; kc < 4; ++kc)
          accD[t] = __builtin_amdgcn_mfma_f32_16x16x32_bf16(af[kc], bfri[t][kc], accD[t], 0, 0, 0);
      if (i >= 2) {
        bf16x8 ah[4];
        #pragma unroll
        for (int kc = 0; kc < 4; ++kc)
          ah[kc] = *(const bf16x8*)&ring2[i & 1][l16 * 136 + kc * 32 + quad * 8];
        #pragma unroll
        for (int t = 0; t < 4; ++t)
          #pragma unroll
          for (int kc = 0; kc < 4; ++kc)
            accD[t] = __builtin_amdgcn_mfma_f32_16x16x32_bf16(ah[kc], bfrh[t][kc], accD[t], 0, 0, 0);
      }
    }

    // B gates -> h1[i]
    u16 hv1[4], hv2[4];
    if (doB) {
      #pragma unroll
      for (int r = 0; r < 4; ++r) {
        const float gi = clampg(accB[0][r] + bf2f(gvb[r][0]));
        const float gf = clampg(accB[1][r] + bf2f(gvb[r][1]));
        const float gg = clampg(accB[2][r] + bf2f(gvb[r][2]));
        const float go = clampg(accB[3][r] + bf2f(gvb[r][3]));
        c1v[r] = sigm(gf) * c1v[r] + sigm(gi) * tanh_fast(gg);
        hv1[r] = f2bf(sigm(go) * tanh_fast(c1v[r]));
      }
    }
    // D gates -> h2[i-1]
    if (doD) {
      #pragma unroll
      for (int r = 0; r < 4; ++r) {
        const float gi = clampg(accD[0][r] + bias2[0]);
        const float gf = clampg(accD[1][r] + bias2[1]);
        const float gg = clampg(accD[2][r] + bias2[2]);
        const float go = clampg(accD[3][r] + bias2[3]);
        c2v[r] = sigm(gf) * c2v[r] + sigm(gi) * tanh_fast(gg);
        hv2[r] = f2bf(sigm(go) * tanh_fast(c2v[r]));
      }
    }

    if (doB) {
      #pragma unroll
      for (int r = 0; r < 4; ++r)
        ring1[i & 1][(quad * 4 + r) * 136 + col] = hv1[r];
    }
    if (doD) {
      #pragma unroll
      for (int r = 0; r < 4; ++r)
        ring2[(i - 1) & 1][(quad * 4 + r) * 136 + col] = hv2[r];
      if (i - 1 == SEQ - 1) {
        #pragma unroll
        for (int r = 0; r < 4; ++r)
          HLAST[((size_t)n * T_STEPS + t0 + quad * 4 + r) * HID + col] = hv2[r];
      }
    }
    __syncthreads();
  }
}

// ---------------------------------------- K3: fc (MFMA) + heads + copy -----
__global__ __launch_bounds__(256) void head_kernel(
    const u16* __restrict__ HLAST, const void* __restrict__ Wfc, const void* __restrict__ bfc,
    const void* __restrict__ Wout0, const void* __restrict__ bout0,
    const void* __restrict__ Wout1, const void* __restrict__ bout1,
    const void* __restrict__ y, const u32* __restrict__ flags,
    float* __restrict__ out)
{
  const int isbf = (int)flags[0];
  const int b = blockIdx.x;
  const int n = b >> 2, tc = (b & 3) * 32;
  const int tid = threadIdx.x;
  const int wave = tid >> 6, lane = tid & 63;
  const int quad = lane >> 4, l16 = lane & 15;

  __shared__ u16 sLA[32 * 136];
  __shared__ float sF[32 * 132];

  for (int i = tid; i < 32 * 128; i += 256) {
    const int r = i >> 7, cc = i & 127;
    const u16 hv = HLAST[((size_t)n * T_STEPS + tc + r) * 128 + cc];
    const float v = bf2f(hv);
    sLA[r * 136 + cc] = v > 0.f ? hv : (u16)0;
  }
  __syncthreads();

  {
    f32x4 acc[2][2];
    #pragma unroll
    for (int mt = 0; mt < 2; ++mt)
      #pragma unroll
      for (int nt = 0; nt < 2; ++nt) { acc[mt][nt][0]=0.f; acc[mt][nt][1]=0.f; acc[mt][nt][2]=0.f; acc[mt][nt][3]=0.f; }
    #pragma unroll
    for (int kc = 0; kc < 4; ++kc) {
      const bf16x8 a0 = *(const bf16x8*)&sLA[l16 * 136 + kc * 32 + quad * 8];
      const bf16x8 a1 = *(const bf16x8*)&sLA[(16 + l16) * 136 + kc * 32 + quad * 8];
      #pragma unroll
      for (int nt = 0; nt < 2; ++nt) {
        const int col = wave * 32 + nt * 16 + l16;
        const bf16x8 bb = ld8(Wfc, (size_t)n * 16384 + (size_t)col * 128 + kc * 32 + quad * 8, isbf);
        acc[0][nt] = __builtin_amdgcn_mfma_f32_16x16x32_bf16(a0, bb, acc[0][nt], 0, 0, 0);
        acc[1][nt] = __builtin_amdgcn_mfma_f32_16x16x32_bf16(a1, bb, acc[1][nt], 0, 0, 0);
      }
    }
    #pragma unroll
    for (int nt = 0; nt < 2; ++nt) {
      const int col = wave * 32 + nt * 16 + l16;
      const float bv = ldf(bfc, n * 128 + col, isbf);
      #pragma unroll
      for (int r = 0; r < 4; ++r) {
        sF[(quad * 4 + r) * 132 + col]      = acc[0][nt][r] + bv;
        sF[(16 + quad * 4 + r) * 132 + col] = acc[1][nt][r] + bv;
      }
    }
  }
  __syncthreads();

  if (tid < 192) {
    const int tt = tid / 6, o = tid % 6;
    size_t wb; float a;
    if (o < 4) { wb = ((size_t)n * 4 + o) * 128;       a = ldf(bout0, n * 4 + o, isbf); }
    else       { wb = ((size_t)n * 2 + (o - 4)) * 128; a = ldf(bout1, n * 2 + o - 4, isbf); }
    for (int k = 0; k < 128; ++k)
      a += sF[tt * 132 + k] * (o < 4 ? ldf(Wout0, wb + k, isbf) : ldf(Wout1, wb + k, isbf));
    const int t = tc + tt;
    if (o < 4) out[((size_t)t * 32 + n) * 4 + o] = a;
    else       out[16384 + ((size_t)t * 32 + n) * 2 + (o - 4)] = a;
  }

  if (tid < 128) {
    const int tt = tid >> 2, k = tid & 3;
    const int t = tc + tt;
    const size_t i = ((size_t)t * 32 + n) * 4 + k;
    out[24576 + i] = ldf(y, i, isbf);
  }
}

// ----------------------------------------------------------------- launch ---
extern "C" void kernel_launch(void* const* d_in, const int* in_sizes, int n_in,
                              void* d_out, int out_size, void* d_ws, size_t ws_size,
                              hipStream_t stream)
{
  (void)out_size;
  static const int DICT_M[22]  = {262144,131072,4096,16384,8192,128,16384,128,
                                  2097152,2097152,16384,16384,2097152,2097152,
                                  16384,16384,524288,4096,16384,128,8192,64};
  static const int DICT_NM[21] = {262144,131072,16384,8192,128,16384,128,
                                  2097152,2097152,16384,16384,2097152,2097152,
                                  16384,16384,524288,4096,16384,128,8192,64};
  static const int SORT_M[22]  = {8192,16384,524288,2097152,2097152,2097152,
                                  2097152,16384,8192,128,128,4096,16384,16384,
                                  16384,16384,128,64,131072,4096,262144,16384};
  static const int SORT_NM[21] = {8192,16384,524288,2097152,2097152,2097152,
                                  2097152,16384,8192,128,128,4096,16384,16384,
                                  16384,16384,128,64,131072,262144,16384};
  auto matches = [&](const int* exp, int cnt, int ei_idx) -> bool {
    if (n_in != cnt) return false;
    for (int i = 0; i < cnt; ++i) {
      if (i == ei_idx) {
        if (in_sizes[i] != 131072 && in_sizes[i] != 262144) return false;
      } else if (in_sizes[i] != exp[i]) return false;
    }
    return true;
  };
  int map[21];
  auto set_dict = [&](int sh) {
    map[0] = 0; map[1] = 1;
    for (int s = 2; s < 21; ++s) map[s] = s + 1 + sh;
  };
  auto set_sorted = [&](int xi) {
    map[0] = xi; map[1] = 18; map[2] = xi + 1;
    map[3] = 0;  map[4] = 9;  map[5] = 1;  map[6] = 10;
    map[7] = 5;  map[8] = 3;  map[9] = 14; map[10] = 12;
    map[11] = 6; map[12] = 4; map[13] = 15; map[14] = 13;
    map[15] = 2; map[16] = 11; map[17] = 7; map[18] = 16;
    map[19] = 8; map[20] = 17;
  };
  if      (matches(DICT_M, 22, 1))  set_dict(0);
  else if (matches(DICT_NM, 21, 1)) set_dict(-1);
  else if (matches(SORT_M, 22, 18)) set_sorted(20);
  else if (matches(SORT_NM, 21, 18)) set_sorted(19);
  else set_dict((n_in >= 22) ? 0 : -1);

  const void* x     = d_in[map[0]];
  const int*  ei    = (const int*)d_in[map[1]];
  const void* y     = d_in[map[2]];
  const void* W1    = d_in[map[3]];
  const void* b1    = d_in[map[4]];
  const void* W2    = d_in[map[5]];
  const void* b2    = d_in[map[6]];
  const void* Wih1  = d_in[map[7]];
  const void* Whh1  = d_in[map[8]];
  const void* bih1  = d_in[map[9]];
  const void* bhh1  = d_in[map[10]];
  const void* Wih2  = d_in[map[11]];
  const void* Whh2  = d_in[map[12]];
  const void* bih2  = d_in[map[13]];
  const void* bhh2  = d_in[map[14]];
  const void* Wfc   = d_in[map[15]];
  const void* bfc   = d_in[map[16]];
  const void* Wout0 = d_in[map[17]];
  const void* bout0 = d_in[map[18]];
  const void* Wout1 = d_in[map[19]];
  const void* bout1 = d_in[map[20]];
  float* out = (float*)d_out;

  // workspace: flags | Hb 1MB | HLAST 1MB | XG1 8MB
  const size_t OFF_HB  = 4096;
  const size_t OFF_HL  = OFF_HB + 1048576;
  const size_t OFF_XG1 = OFF_HL + 1048576;
  const size_t WS_NEED = OFF_XG1 + 8388608;
  if (ws_size < WS_NEED) return;
  char* ws = (char*)d_ws;
  u32* flags  = (u32*)ws;
  u16* Hb     = (u16*)(ws + OFF_HB);
  u16* HLAST  = (u16*)(ws + OFF_HL);
  u16* XG1    = (u16*)(ws + OFF_XG1);

  gcn_kernel <<<dim3(128), dim3(512), 0, stream>>>(x, ei, W1, b1, W2, b2, flags, Hb);
  lstm_kernel<<<dim3(256), dim3(512), 0, stream>>>(Wih1, Whh1, Wih2, Whh2,
                                                   bih1, bhh1, bih2, bhh2,
                                                   Hb, flags, XG1, HLAST);
  head_kernel<<<dim3(128), dim3(256), 0, stream>>>(HLAST, Wfc, bfc, Wout0, bout0,
                                                   Wout1, bout1, y, flags, out);
}

// Round 11
// 195.810 us; speedup vs baseline: 1.1387x; 1.1387x over previous
//
#include <hip/hip_runtime.h>

// STGCN-LSTM-Node on MI355X (gfx950).
// T=128, N=32, E=512/t, IN_C=64, HID=128, SEQ=16, heads (4,2).
// d_out is FLOAT32: [out0 16384][out1 8192][targets 16384].
//
// R20: head_kernel ELIMINATED (fused into lstm tail); lstm reverted to R18
//   (best, 83us; R19 merge was neutral/negative). fc input = relu(h2@l=15)
//   [16x128], in LDS at end of phase D -> 4 MFMAs/wave + 96-thread head
//   dots. Kills: 1 launch, HLAST round-trip, head re-staging. targets-copy
//   moved to gcn. gcn staging: raw u16 copy when isbf (f2bf(bf2f())
//   identity round-trip removed, ~6 VALU x 26K elems/block).
//   Cross-round ledger: total - lstm has been ~134us every round -> gcn +
//   head + overhead. This round makes head's share = 0 and measurable.
//
// flags[0]=1: float inputs stored as bf16-u16; =0: f32
// flags[1]=1: edge_index int64; =0: int32

#define T_STEPS 128
#define HID     128
#define G4      512
#define SEQ     16

typedef unsigned short u16;
typedef unsigned int   u32;
typedef __attribute__((ext_vector_type(8))) short bf16x8;
typedef __attribute__((ext_vector_type(4))) float f32x4;
typedef __attribute__((ext_vector_type(4))) u16   u16x4;

__device__ __forceinline__ float bf2f(u16 u) {
  union { u32 i; float f; } v; v.i = ((u32)u) << 16; return v.f;
}
__device__ __forceinline__ u16 f2bf(float f) {
  union { u32 i; float f; } v; v.f = f;
  const u32 i = v.i;
  return (u16)((i + 0x7fffu + ((i >> 16) & 1u)) >> 16);
}
__device__ __forceinline__ float sigm(float x) {
  return __builtin_amdgcn_rcpf(1.f + __expf(-x));
}
__device__ __forceinline__ float tanh_fast(float x) {
  return 1.f - 2.f * __builtin_amdgcn_rcpf(1.f + __expf(2.f * x));
}
__device__ __forceinline__ float clampg(float x) { return fminf(fmaxf(x, -25.f), 25.f); }

__device__ __forceinline__ float ldf(const void* p, size_t i, int isbf) {
  return isbf ? bf2f(((const u16*)p)[i]) : ((const float*)p)[i];
}
__device__ __forceinline__ bf16x8 ld8(const void* p, size_t o, int isbf) {
  if (isbf) return *(const bf16x8*)((const u16*)p + o);
  const float* f = (const float*)p + o;
  bf16x8 r;
  #pragma unroll
  for (int j = 0; j < 8; ++j) r[j] = (short)f2bf(f[j]);
  return r;
}
__device__ __forceinline__ int lde(const int* ei, int idx, int i64) {
  return i64 ? ei[idx * 2] : ei[idx];
}

// ----------------------------------------- K1: GCN (MFMA, self-detect) -----
__global__ __launch_bounds__(512) void gcn_kernel(
    const void* __restrict__ x, const int* __restrict__ ei,
    const void* __restrict__ W1, const void* __restrict__ b1,
    const void* __restrict__ W2, const void* __restrict__ b2,
    const void* __restrict__ y, u32* __restrict__ flags,
    u16* __restrict__ Hb, float* __restrict__ out)
{
  const int t = blockIdx.x;
  const int tid = threadIdx.x;
  const int wave = tid >> 6, lane = tid & 63;
  const int quad = lane >> 4, l16 = lane & 15;

  __shared__ u16 sXA[32 * 72];
  __shared__ u16 sW1T[128 * 72];
  __shared__ u16 sW2T[128 * 136];
  __shared__ u16 sAmB[32 * 40];
  __shared__ float sAm[32 * 33];
  __shared__ u16 sT[128 * 40];
  __shared__ u16 sHA[32 * 136];
  __shared__ int sdeg[32];
  __shared__ float sdinv[32];
  __shared__ int dc1, dc2;

  if (tid == 0) { dc1 = 0; dc2 = 0; }
  __syncthreads();
  if (tid < 256) {
    const u32 w = ((const u32*)x)[tid];
    const u16 lo = (u16)(w & 0xffffu);
    const float a = fabsf(bf2f(lo));
    if (lo != 0 && a >= 9.5e-7f && a <= 8.f) atomicAdd(&dc1, 1);
    if (ei[2 * tid + 1] != 0) atomicAdd(&dc2, 1);
  }
  __syncthreads();
  const int isbf = (dc1 >= 128) ? 1 : 0;
  const int i64  = (dc2 < 8) ? 1 : 0;
  if (t == 0 && tid == 0) { flags[0] = (u32)isbf; flags[1] = (u32)i64; }

  // targets copy (moved from head_kernel): 128 floats per t
  if (tid < 128) out[24576 + t * 128 + tid] = ldf(y, (size_t)t * 128 + tid, isbf);

  // ---- staging (isbf: raw u16 copy; no f2bf(bf2f()) round trip) ----
  if (isbf) {
    const u16* xu  = (const u16*)x;
    const u16* w1u = (const u16*)W1;
    const u16* w2u = (const u16*)W2;
    for (int v = tid; v < 256; v += 512) {
      const int m = v >> 3, k8 = (v & 7) * 8;
      *(bf16x8*)&sXA[m * 72 + k8] = *(const bf16x8*)&xu[(size_t)t * 2048 + m * 64 + k8];
    }
    for (int idx = tid; idx < 8192; idx += 512) {
      const int k = idx >> 7, nn = idx & 127;
      sW1T[nn * 72 + k] = w1u[idx];
    }
    for (int idx = tid; idx < 16384; idx += 512) {
      const int k = idx >> 7, nn = idx & 127;
      sW2T[nn * 136 + k] = w2u[idx];
    }
  } else {
    for (int idx = tid; idx < 2048; idx += 512) {
      const int m = idx >> 6, k = idx & 63;
      sXA[m * 72 + k] = f2bf(ldf(x, (size_t)t * 2048 + idx, 0));
    }
    for (int idx = tid; idx < 8192; idx += 512) {
      const int k = idx >> 7, nn = idx & 127;
      sW1T[nn * 72 + k] = f2bf(ldf(W1, idx, 0));
    }
    for (int idx = tid; idx < 16384; idx += 512) {
      const int k = idx >> 7, nn = idx & 127;
      sW2T[nn * 136 + k] = f2bf(ldf(W2, idx, 0));
    }
  }
  for (int i = tid; i < 32 * 33; i += 512) sAm[i] = 0.f;
  if (tid < 32) sdeg[tid] = 0;
  __syncthreads();
  if (tid < 512) {
    const int cd = lde(ei, t * 1024 + 512 + tid, i64);
    if ((u32)cd < 32u) atomicAdd(&sdeg[cd], 1);
  }
  __syncthreads();
  if (tid < 32) sdinv[tid] = rsqrtf((float)(sdeg[tid] + 1));
  __syncthreads();
  if (tid < 512) {
    const int r  = lde(ei, t * 1024 + tid, i64);
    const int cd = lde(ei, t * 1024 + 512 + tid, i64);
    if ((u32)r < 32u && (u32)cd < 32u)
      atomicAdd(&sAm[cd * 33 + r], sdinv[r] * sdinv[cd]);
  }
  if (tid < 32) atomicAdd(&sAm[tid * 33 + tid], sdinv[tid] * sdinv[tid]);
  __syncthreads();

  for (int idx = tid; idx < 1024; idx += 512) {
    const int m = idx >> 5, k = idx & 31;
    sAmB[m * 40 + k] = f2bf(sAm[m * 33 + k]);
  }
  // GEMM1
  {
    const int nc = wave * 16 + l16;
    f32x4 c0 = {0.f,0.f,0.f,0.f}, c1 = {0.f,0.f,0.f,0.f};
    #pragma unroll
    for (int kc = 0; kc < 2; ++kc) {
      const bf16x8 a0 = *(const bf16x8*)&sXA[l16 * 72 + kc * 32 + quad * 8];
      const bf16x8 a1 = *(const bf16x8*)&sXA[(16 + l16) * 72 + kc * 32 + quad * 8];
      const bf16x8 bb = *(const bf16x8*)&sW1T[nc * 72 + kc * 32 + quad * 8];
      c0 = __builtin_amdgcn_mfma_f32_16x16x32_bf16(a0, bb, c0, 0, 0, 0);
      c1 = __builtin_amdgcn_mfma_f32_16x16x32_bf16(a1, bb, c1, 0, 0, 0);
    }
    #pragma unroll
    for (int r = 0; r < 4; ++r) {
      sT[nc * 40 + quad * 4 + r]      = f2bf(c0[r]);
      sT[nc * 40 + 16 + quad * 4 + r] = f2bf(c1[r]);
    }
  }
  __syncthreads();
  // GEMM2
  {
    const int nc = wave * 16 + l16;
    const bf16x8 a0 = *(const bf16x8*)&sAmB[l16 * 40 + quad * 8];
    const bf16x8 a1 = *(const bf16x8*)&sAmB[(16 + l16) * 40 + quad * 8];
    const bf16x8 bb = *(const bf16x8*)&sT[nc * 40 + quad * 8];
    f32x4 c0 = {0.f,0.f,0.f,0.f}, c1 = {0.f,0.f,0.f,0.f};
    c0 = __builtin_amdgcn_mfma_f32_16x16x32_bf16(a0, bb, c0, 0, 0, 0);
    c1 = __builtin_amdgcn_mfma_f32_16x16x32_bf16(a1, bb, c1, 0, 0, 0);
    const float bv = ldf(b1, nc, isbf);
    #pragma unroll
    for (int r = 0; r < 4; ++r) {
      float v0 = c0[r] + bv, v1 = c1[r] + bv;
      sHA[(quad * 4 + r) * 136 + nc]      = f2bf(v0 > 0.f ? v0 : 0.f);
      sHA[(16 + quad * 4 + r) * 136 + nc] = f2bf(v1 > 0.f ? v1 : 0.f);
    }
  }
  __syncthreads();
  // GEMM3
  {
    const int nc = wave * 16 + l16;
    f32x4 c0 = {0.f,0.f,0.f,0.f}, c1 = {0.f,0.f,0.f,0.f};
    #pragma unroll
    for (int kc = 0; kc < 4; ++kc) {
      const bf16x8 a0 = *(const bf16x8*)&sHA[l16 * 136 + kc * 32 + quad * 8];
      const bf16x8 a1 = *(const bf16x8*)&sHA[(16 + l16) * 136 + kc * 32 + quad * 8];
      const bf16x8 bb = *(const bf16x8*)&sW2T[nc * 136 + kc * 32 + quad * 8];
      c0 = __builtin_amdgcn_mfma_f32_16x16x32_bf16(a0, bb, c0, 0, 0, 0);
      c1 = __builtin_amdgcn_mfma_f32_16x16x32_bf16(a1, bb, c1, 0, 0, 0);
    }
    #pragma unroll
    for (int r = 0; r < 4; ++r) {
      sT[nc * 40 + quad * 4 + r]      = f2bf(c0[r]);
      sT[nc * 40 + 16 + quad * 4 + r] = f2bf(c1[r]);
    }
  }
  __syncthreads();
  // GEMM4
  {
    const int nc = wave * 16 + l16;
    const bf16x8 a0 = *(const bf16x8*)&sAmB[l16 * 40 + quad * 8];
    const bf16x8 a1 = *(const bf16x8*)&sAmB[(16 + l16) * 40 + quad * 8];
    const bf16x8 bb = *(const bf16x8*)&sT[nc * 40 + quad * 8];
    f32x4 c0 = {0.f,0.f,0.f,0.f}, c1 = {0.f,0.f,0.f,0.f};
    c0 = __builtin_amdgcn_mfma_f32_16x16x32_bf16(a0, bb, c0, 0, 0, 0);
    c1 = __builtin_amdgcn_mfma_f32_16x16x32_bf16(a1, bb, c1, 0, 0, 0);
    const float bv = ldf(b2, nc, isbf);
    #pragma unroll
    for (int r = 0; r < 4; ++r) {
      float v0 = c0[r] + bv, v1 = c1[r] + bv;
      Hb[((size_t)t * 32 + quad * 4 + r) * 128 + nc]      = f2bf(v0 > 0.f ? v0 : 0.f);
      Hb[((size_t)t * 32 + 16 + quad * 4 + r) * 128 + nc] = f2bf(v1 > 0.f ? v1 : 0.f);
    }
  }
}

// --------------- K2 (R20): R18 lstm + fused fc/heads tail ------------------
// Arena (131072 B, forces 1 block/CU -> big register budget):
//   [0,     8704)  sHB [32][136] (phase A)  -> reused as sLast [16][136] (tail)
//   [8704, 41472)  xg1 [32][128][4] u16 (A->B) -> reused as sF float[16][132]
//   [41472,111104) h1seq [16][16][136] u16 (B->D)
// + sH ping-pong [2][16*136] (phase D h2 state).
// Weights pinned in AGPRs ("+a"): MFMA reads AGPR operands natively.
__global__ __launch_bounds__(512) void lstm_kernel(
    const void* __restrict__ Wih1, const void* __restrict__ Whh1,
    const void* __restrict__ Wih2, const void* __restrict__ Whh2,
    const void* __restrict__ bih1, const void* __restrict__ bhh1,
    const void* __restrict__ bih2, const void* __restrict__ bhh2,
    const u16* __restrict__ Hb, const u32* __restrict__ flags,
    const void* __restrict__ Wfc, const void* __restrict__ bfc,
    const void* __restrict__ Wout0, const void* __restrict__ bout0,
    const void* __restrict__ Wout1, const void* __restrict__ bout1,
    float* __restrict__ out)
{
  const int isbf = (int)flags[0];
  const int b = blockIdx.x;
  const int n = b & 31, wg = b >> 5;
  const int t0 = wg * 16;
  const int tid = threadIdx.x;
  const int wave = tid >> 6, lane = tid & 63;
  const int quad = lane >> 4, l16 = lane & 15;
  const int col = wave * 16 + l16;

  __shared__ __align__(16) char arena[131072];
  __shared__ __align__(16) u16 sH[2][16 * 136];
  u16*  sHB   = (u16*)arena;
  u16*  sLast = (u16*)arena;                 // tail reuse of sHB region
  u16*  xg1L  = (u16*)(arena + 8704);
  float* sF   = (float*)(arena + 8704);      // tail reuse of xg1L region
  u16*  h1sL  = (u16*)(arena + 41472);

  const size_t Wbase = (size_t)n * (G4 * HID);

  // ---- phase A: stage Hb window; XG1 gate-packed -> LDS ----
  for (int idx = tid; idx < 32 * 128; idx += 512) {
    const int row = idx >> 7, cc = idx & 127;
    const int tp = t0 - 15 + row;
    sHB[row * 136 + cc] =
        (tp >= 0 && tp < T_STEPS) ? Hb[((size_t)tp * 32 + n) * 128 + cc] : (u16)0;
  }
  float bbv[4];
  #pragma unroll
  for (int t = 0; t < 4; ++t)
    bbv[t] = ldf(bih1, n * 512 + t * 128 + col, isbf) +
             ldf(bhh1, n * 512 + t * 128 + col, isbf);
  __syncthreads();
  {
    u16 pk[2][4][4];   // [grp][r][gate]
    #pragma unroll
    for (int t = 0; t < 4; ++t) {
      const size_t gb = Wbase + (size_t)(t * 128 + col) * HID;
      f32x4 a0 = {0.f,0.f,0.f,0.f}, a1 = {0.f,0.f,0.f,0.f};
      #pragma unroll
      for (int kc = 0; kc < 4; ++kc) {
        const bf16x8 wf = ld8(Wih1, gb + kc * 32 + quad * 8, isbf);
        const bf16x8 h0 = *(const bf16x8*)&sHB[l16 * 136 + kc * 32 + quad * 8];
        const bf16x8 h1v = *(const bf16x8*)&sHB[(16 + l16) * 136 + kc * 32 + quad * 8];
        a0 = __builtin_amdgcn_mfma_f32_16x16x32_bf16(h0, wf, a0, 0, 0, 0);
        a1 = __builtin_amdgcn_mfma_f32_16x16x32_bf16(h1v, wf, a1, 0, 0, 0);
      }
      #pragma unroll
      for (int r = 0; r < 4; ++r) {
        pk[0][r][t] = f2bf(a0[r] + bbv[t]);
        pk[1][r][t] = f2bf(a1[r] + bbv[t]);
      }
    }
    #pragma unroll
    for (int g2 = 0; g2 < 2; ++g2)
      #pragma unroll
      for (int r = 0; r < 4; ++r) {
        u16x4 v = {pk[g2][r][0], pk[g2][r][1], pk[g2][r][2], pk[g2][r][3]};
        *(u16x4*)&xg1L[((size_t)(g2 * 16 + quad * 4 + r) * 128 + col) * 4] = v;
      }
  }

  // ---- Whh1 -> 64 pinned AGPRs ----
  bf16x8 bfr1[4][4];
  #pragma unroll
  for (int t = 0; t < 4; ++t) {
    const size_t gb = Wbase + (size_t)(t * 128 + col) * HID;
    #pragma unroll
    for (int kc = 0; kc < 4; ++kc)
      bfr1[t][kc] = ld8(Whh1, gb + kc * 32 + quad * 8, isbf);
  }
  #pragma unroll
  for (int t = 0; t < 4; ++t)
    #pragma unroll
    for (int kc = 0; kc < 4; ++kc)
      asm volatile("" : "+a"(bfr1[t][kc]));

  float c1v[4] = {0.f, 0.f, 0.f, 0.f};
  __syncthreads();   // xg1L ready; sHB reads done

  // ---- phase B: L1 recurrence; h1[l] -> h1sL; 1 barrier/step ----
  for (int l = 0; l < SEQ; ++l) {
    f32x4 acc[4];
    #pragma unroll
    for (int t = 0; t < 4; ++t) { acc[t][0]=0.f; acc[t][1]=0.f; acc[t][2]=0.f; acc[t][3]=0.f; }
    if (l) {
      bf16x8 af[4];
      #pragma unroll
      for (int kc = 0; kc < 4; ++kc)
        af[kc] = *(const bf16x8*)&h1sL[(l - 1) * 2176 + l16 * 136 + kc * 32 + quad * 8];
      #pragma unroll
      for (int t = 0; t < 4; ++t)
        #pragma unroll
        for (int kc = 0; kc < 4; ++kc)
          acc[t] = __builtin_amdgcn_mfma_f32_16x16x32_bf16(af[kc], bfr1[t][kc], acc[t], 0, 0, 0);
    }
    #pragma unroll
    for (int r = 0; r < 4; ++r) {
      const int row = quad * 4 + r + l;
      const u16x4 gv = *(const u16x4*)&xg1L[((size_t)row * 128 + col) * 4];
      const float gi = clampg(acc[0][r] + bf2f(gv[0]));
      const float gf = clampg(acc[1][r] + bf2f(gv[1]));
      const float gg = clampg(acc[2][r] + bf2f(gv[2]));
      const float go = clampg(acc[3][r] + bf2f(gv[3]));
      c1v[r] = sigm(gf) * c1v[r] + sigm(gi) * tanh_fast(gg);
      h1sL[l * 2176 + (quad * 4 + r) * 136 + col] = f2bf(sigm(go) * tanh_fast(c1v[r]));
    }
    __syncthreads();
  }

  // ---- Wih2 + Whh2 -> 128 pinned AGPRs (bfr1 dead, regs reused) ----
  bf16x8 bfri[4][4], bfrh[4][4];
  #pragma unroll
  for (int t = 0; t < 4; ++t) {
    const size_t gb = Wbase + (size_t)(t * 128 + col) * HID;
    #pragma unroll
    for (int kc = 0; kc < 4; ++kc) {
      bfri[t][kc] = ld8(Wih2, gb + kc * 32 + quad * 8, isbf);
      bfrh[t][kc] = ld8(Whh2, gb + kc * 32 + quad * 8, isbf);
    }
  }
  #pragma unroll
  for (int t = 0; t < 4; ++t)
    #pragma unroll
    for (int kc = 0; kc < 4; ++kc) {
      asm volatile("" : "+a"(bfri[t][kc]));
      asm volatile("" : "+a"(bfrh[t][kc]));
    }

  float bias2[4];
  #pragma unroll
  for (int t = 0; t < 4; ++t)
    bias2[t] = ldf(bih2, n * 512 + t * 128 + col, isbf) +
               ldf(bhh2, n * 512 + t * 128 + col, isbf);

  // ---- phase D: L2 recurrence, all-AGPR weights; 1 barrier/step ----
  float c2v[4] = {0.f, 0.f, 0.f, 0.f};
  int p = 0;
  for (int s = 0; s < SEQ; ++s) {
    bf16x8 af[4];
    #pragma unroll
    for (int kc = 0; kc < 4; ++kc)
      af[kc] = *(const bf16x8*)&h1sL[s * 2176 + l16 * 136 + kc * 32 + quad * 8];
    f32x4 acc[4];
    #pragma unroll
    for (int t = 0; t < 4; ++t) { acc[t][0]=0.f; acc[t][1]=0.f; acc[t][2]=0.f; acc[t][3]=0.f; }
    #pragma unroll
    for (int t = 0; t < 4; ++t)
      #pragma unroll
      for (int kc = 0; kc < 4; ++kc)
        acc[t] = __builtin_amdgcn_mfma_f32_16x16x32_bf16(af[kc], bfri[t][kc], acc[t], 0, 0, 0);
    if (s) {
      bf16x8 ah[4];
      #pragma unroll
      for (int kc = 0; kc < 4; ++kc)
        ah[kc] = *(const bf16x8*)&sH[p][l16 * 136 + kc * 32 + quad * 8];
      #pragma unroll
      for (int t = 0; t < 4; ++t)
        #pragma unroll
        for (int kc = 0; kc < 4; ++kc)
          acc[t] = __builtin_amdgcn_mfma_f32_16x16x32_bf16(ah[kc], bfrh[t][kc], acc[t], 0, 0, 0);
    }
    u16 hv[4];
    #pragma unroll
    for (int r = 0; r < 4; ++r) {
      const float gi = clampg(acc[0][r] + bias2[0]);
      const float gf = clampg(acc[1][r] + bias2[1]);
      const float gg = clampg(acc[2][r] + bias2[2]);
      const float go = clampg(acc[3][r] + bias2[3]);
      c2v[r] = sigm(gf) * c2v[r] + sigm(gi) * tanh_fast(gg);
      hv[r] = f2bf(sigm(go) * tanh_fast(c2v[r]));
    }
    #pragma unroll
    for (int r = 0; r < 4; ++r) {
      sH[1 - p][(quad * 4 + r) * 136 + col] = hv[r];
      if (s == SEQ - 1)   // relu'd final h2 for the fc tail (bf16 relu = sign test)
        sLast[(quad * 4 + r) * 136 + col] = (hv[r] & 0x8000u) ? (u16)0 : hv[r];
    }
    __syncthreads();
    p ^= 1;
  }

  // ---- fused fc + heads tail (replaces head_kernel) ----
  {
    f32x4 acc = {0.f, 0.f, 0.f, 0.f};
    #pragma unroll
    for (int kc = 0; kc < 4; ++kc) {
      const bf16x8 a  = *(const bf16x8*)&sLast[l16 * 136 + kc * 32 + quad * 8];
      const bf16x8 bb = ld8(Wfc, (size_t)n * 16384 + (size_t)col * 128 + kc * 32 + quad * 8, isbf);
      acc = __builtin_amdgcn_mfma_f32_16x16x32_bf16(a, bb, acc, 0, 0, 0);
    }
    const float bv = ldf(bfc, n * 128 + col, isbf);
    #pragma unroll
    for (int r = 0; r < 4; ++r)
      sF[(quad * 4 + r) * 132 + col] = acc[r] + bv;
  }
  __syncthreads();
  if (tid < 96) {
    const int tt = tid / 6, o = tid % 6;
    size_t wb; float a;
    if (o < 4) { wb = ((size_t)n * 4 + o) * 128;       a = ldf(bout0, n * 4 + o, isbf); }
    else       { wb = ((size_t)n * 2 + (o - 4)) * 128; a = ldf(bout1, n * 2 + o - 4, isbf); }
    for (int k8 = 0; k8 < 16; ++k8) {
      const bf16x8 wv = ld8(o < 4 ? Wout0 : Wout1, wb + k8 * 8, isbf);
      #pragma unroll
      for (int j = 0; j < 8; ++j) a += sF[tt * 132 + k8 * 8 + j] * bf2f((u16)wv[j]);
    }
    const int t = t0 + tt;
    if (o < 4) out[((size_t)t * 32 + n) * 4 + o] = a;
    else       out[16384 + ((size_t)t * 32 + n) * 2 + (o - 4)] = a;
  }
}

// ----------------------------------------------------------------- launch ---
extern "C" void kernel_launch(void* const* d_in, const int* in_sizes, int n_in,
                              void* d_out, int out_size, void* d_ws, size_t ws_size,
                              hipStream_t stream)
{
  (void)out_size;
  static const int DICT_M[22]  = {262144,131072,4096,16384,8192,128,16384,128,
                                  2097152,2097152,16384,16384,2097152,2097152,
                                  16384,16384,524288,4096,16384,128,8192,64};
  static const int DICT_NM[21] = {262144,131072,16384,8192,128,16384,128,
                                  2097152,2097152,16384,16384,2097152,2097152,
                                  16384,16384,524288,4096,16384,128,8192,64};
  static const int SORT_M[22]  = {8192,16384,524288,2097152,2097152,2097152,
                                  2097152,16384,8192,128,128,4096,16384,16384,
                                  16384,16384,128,64,131072,4096,262144,16384};
  static const int SORT_NM[21] = {8192,16384,524288,2097152,2097152,2097152,
                                  2097152,16384,8192,128,128,4096,16384,16384,
                                  16384,16384,128,64,131072,262144,16384};
  auto matches = [&](const int* exp, int cnt, int ei_idx) -> bool {
    if (n_in != cnt) return false;
    for (int i = 0; i < cnt; ++i) {
      if (i == ei_idx) {
        if (in_sizes[i] != 131072 && in_sizes[i] != 262144) return false;
      } else if (in_sizes[i] != exp[i]) return false;
    }
    return true;
  };
  int map[21];
  auto set_dict = [&](int sh) {
    map[0] = 0; map[1] = 1;
    for (int s = 2; s < 21; ++s) map[s] = s + 1 + sh;
  };
  auto set_sorted = [&](int xi) {
    map[0] = xi; map[1] = 18; map[2] = xi + 1;
    map[3] = 0;  map[4] = 9;  map[5] = 1;  map[6] = 10;
    map[7] = 5;  map[8] = 3;  map[9] = 14; map[10] = 12;
    map[11] = 6; map[12] = 4; map[13] = 15; map[14] = 13;
    map[15] = 2; map[16] = 11; map[17] = 7; map[18] = 16;
    map[19] = 8; map[20] = 17;
  };
  if      (matches(DICT_M, 22, 1))  set_dict(0);
  else if (matches(DICT_NM, 21, 1)) set_dict(-1);
  else if (matches(SORT_M, 22, 18)) set_sorted(20);
  else if (matches(SORT_NM, 21, 18)) set_sorted(19);
  else set_dict((n_in >= 22) ? 0 : -1);

  const void* x     = d_in[map[0]];
  const int*  ei    = (const int*)d_in[map[1]];
  const void* y     = d_in[map[2]];
  const void* W1    = d_in[map[3]];
  const void* b1    = d_in[map[4]];
  const void* W2    = d_in[map[5]];
  const void* b2    = d_in[map[6]];
  const void* Wih1  = d_in[map[7]];
  const void* Whh1  = d_in[map[8]];
  const void* bih1  = d_in[map[9]];
  const void* bhh1  = d_in[map[10]];
  const void* Wih2  = d_in[map[11]];
  const void* Whh2  = d_in[map[12]];
  const void* bih2  = d_in[map[13]];
  const void* bhh2  = d_in[map[14]];
  const void* Wfc   = d_in[map[15]];
  const void* bfc   = d_in[map[16]];
  const void* Wout0 = d_in[map[17]];
  const void* bout0 = d_in[map[18]];
  const void* Wout1 = d_in[map[19]];
  const void* bout1 = d_in[map[20]];
  float* out = (float*)d_out;

  const size_t WS_NEED = 4096 + 1048576;
  if (ws_size < WS_NEED) return;
  char* ws = (char*)d_ws;
  u32* flags  = (u32*)ws;
  u16* Hb     = (u16*)(ws + 4096);

  gcn_kernel <<<dim3(128), dim3(512), 0, stream>>>(x, ei, W1, b1, W2, b2, y, flags, Hb, out);
  lstm_kernel<<<dim3(256), dim3(512), 0, stream>>>(Wih1, Whh1, Wih2, Whh2,
                                                   bih1, bhh1, bih2, bhh2,
                                                   Hb, flags,
                                                   Wfc, bfc, Wout0, bout0, Wout1, bout1,
                                                   out);
}